// Round 8
// baseline (5107.866 us; speedup 1.0000x reference)
//
#include <hip/hip_runtime.h>
#include <hip/hip_bf16.h>
#include <cmath>

#define NB   16
#define LL   1024
#define DD   512
#define NCLS 64

// ---------------------------------------------- fused embed-gather + proj GEMM
__global__ __launch_bounds__(256) void k_gemm_embed(
    const int* __restrict__ x, const float* __restrict__ emb,
    const float* __restrict__ W, const float* __restrict__ b1,
    const float* __restrict__ b2, float* __restrict__ C)
{
  __shared__ __align__(16) float As[32][68];
  __shared__ __align__(16) float Ws[32][68];
  const int tid = threadIdx.x;
  const int n0 = (blockIdx.x & 7) * 64;
  const int m0 = (blockIdx.x >> 3) * 64;
  const int tm = tid & 15, tn = tid >> 4;
  float acc[4][4] = {};

  const int f0 = tid * 2, f1 = tid * 2 + 1;
  const int r0 = f0 >> 3, q0 = f0 & 7;
  const int r1 = f1 >> 3, q1 = f1 & 7;
  const long arow0 = (long)x[m0 + r0] * DD;
  const long arow1 = (long)x[m0 + r1] * DD;
  const long wrow0 = (long)(n0 + r0) * DD;
  const long wrow1 = (long)(n0 + r1) * DD;

  for (int k0 = 0; k0 < DD; k0 += 32) {
    float4 va = *(const float4*)(emb + arow0 + k0 + q0 * 4);
    float4 vb = *(const float4*)(emb + arow1 + k0 + q1 * 4);
    float4 wa = *(const float4*)(W + wrow0 + k0 + q0 * 4);
    float4 wb = *(const float4*)(W + wrow1 + k0 + q1 * 4);
    __syncthreads();
    As[q0*4+0][r0]=va.x; As[q0*4+1][r0]=va.y; As[q0*4+2][r0]=va.z; As[q0*4+3][r0]=va.w;
    As[q1*4+0][r1]=vb.x; As[q1*4+1][r1]=vb.y; As[q1*4+2][r1]=vb.z; As[q1*4+3][r1]=vb.w;
    Ws[q0*4+0][r0]=wa.x; Ws[q0*4+1][r0]=wa.y; Ws[q0*4+2][r0]=wa.z; Ws[q0*4+3][r0]=wa.w;
    Ws[q1*4+0][r1]=wb.x; Ws[q1*4+1][r1]=wb.y; Ws[q1*4+2][r1]=wb.z; Ws[q1*4+3][r1]=wb.w;
    __syncthreads();
    #pragma unroll
    for (int kk = 0; kk < 32; ++kk) {
      float4 a = *(const float4*)&As[kk][tm * 4];
      float4 w = *(const float4*)&Ws[kk][tn * 4];
      acc[0][0]+=a.x*w.x; acc[0][1]+=a.x*w.y; acc[0][2]+=a.x*w.z; acc[0][3]+=a.x*w.w;
      acc[1][0]+=a.y*w.x; acc[1][1]+=a.y*w.y; acc[1][2]+=a.y*w.z; acc[1][3]+=a.y*w.w;
      acc[2][0]+=a.z*w.x; acc[2][1]+=a.z*w.y; acc[2][2]+=a.z*w.z; acc[2][3]+=a.z*w.w;
      acc[3][0]+=a.w*w.x; acc[3][1]+=a.w*w.y; acc[3][2]+=a.w*w.z; acc[3][3]+=a.w*w.w;
    }
  }
  float bj[4];
  #pragma unroll
  for (int j = 0; j < 4; ++j)
    bj[j] = b1[n0 + tn * 4 + j] + b2[n0 + tn * 4 + j];
  #pragma unroll
  for (int i = 0; i < 4; ++i) {
    const int m = m0 + tm * 4 + i;
    float4 o = { acc[i][0]+bj[0], acc[i][1]+bj[1], acc[i][2]+bj[2], acc[i][3]+bj[3] };
    *(float4*)(C + (long)m * DD + n0 + tn * 4) = o;
  }
}

// ---------------------------------------------------------------- scan helpers
__device__ __forceinline__ float wave_red8(float y) {
  y += __int_as_float(__builtin_amdgcn_ds_swizzle(__float_as_int(y), 0x041F));
  y += __int_as_float(__builtin_amdgcn_ds_swizzle(__float_as_int(y), 0x081F));
  y += __int_as_float(__builtin_amdgcn_ds_swizzle(__float_as_int(y), 0x101F));
  return y;
}
__device__ __forceinline__ unsigned long long ald64(const float* p) {
  return __hip_atomic_load((const unsigned long long*)p, __ATOMIC_RELAXED,
                           __HIP_MEMORY_SCOPE_AGENT);
}
__device__ __forceinline__ void enc_st(float* p, float v) {   // slow path: IF$
  __hip_atomic_store(p, v + 2.0f, __ATOMIC_RELAXED, __HIP_MEMORY_SCOPE_AGENT);
}
__device__ __forceinline__ void fast_st(float* p, float v) {  // plain store -> local L2
  __hip_atomic_store(p, v, __ATOMIC_RELAXED, __HIP_MEMORY_SCOPE_WORKGROUP);
}
__device__ __forceinline__ float u64lo(unsigned long long u) {
  return __uint_as_float((unsigned)u);
}
__device__ __forceinline__ float u64hi(unsigned long long u) {
  return __uint_as_float((unsigned)(u >> 32));
}
// 32B sc0 load (L1-bypass, served by local L2), issue+wait in ONE asm
// (compiles on gfx950; split tied-operand wait does NOT — r7).
__device__ __forceinline__ void ld2x16_sc0(const float* p, float4& a, float4& b) {
  asm volatile("global_load_dwordx4 %0, %2, off sc0\n\t"
               "global_load_dwordx4 %1, %2, off offset:16 sc0\n\t"
               "s_waitcnt vmcnt(0)"
               : "=v"(a), "=v"(b) : "v"(p) : "memory");
}
__device__ __forceinline__ bool rdy8(const float4& a, const float4& b) {
  float m = fminf(fminf(fminf(a.x, a.y), fminf(a.z, a.w)),
                  fminf(fminf(b.x, b.y), fminf(b.z, b.w)));
  return m > 1.0f;
}
__device__ __forceinline__ float4 s4(const float4& a, float s) {
  return make_float4(s * a.x, s * a.y, s * a.z, s * a.w);
}
__device__ __forceinline__ float bl(unsigned u) { return __uint_as_float(u << 16); }
__device__ __forceinline__ float bh(unsigned u) { return __uint_as_float(u & 0xffff0000u); }
__device__ __forceinline__ unsigned short b16(float a) {
  __hip_bfloat16 h = __float2bfloat16(a);
  return *reinterpret_cast<unsigned short*>(&h);
}
__device__ __forceinline__ unsigned pk(float a, float b) {
  return (unsigned)b16(a) | ((unsigned)b16(b) << 16);
}
__device__ __forceinline__ float fast_tanh(float x) {
  float e = __expf(2.0f * x);
  return 1.0f - 2.0f / (e + 1.0f);
}
__device__ __forceinline__ float dot64_bf16(const uint4* Wp, int ctid, const float* hslice) {
  const float4* hp = (const float4*)hslice;
  float y0 = 0.f, y1 = 0.f, y2 = 0.f, y3 = 0.f;
  #pragma unroll
  for (int t4 = 0; t4 < 8; ++t4) {
    uint4 u = Wp[t4 * 128 + ctid];
    float4 ha = hp[2 * t4], hb = hp[2 * t4 + 1];
    y0 += bl(u.x) * ha.x; y1 += bh(u.x) * ha.y;
    y2 += bl(u.y) * ha.z; y3 += bh(u.y) * ha.w;
    y0 += bl(u.z) * hb.x; y1 += bh(u.z) * hb.y;
    y2 += bl(u.w) * hb.z; y3 += bh(u.w) * hb.w;
  }
  return (y0 + y1) + (y2 + y3);
}

// ------------------------------------------------- persistent 2-layer RNN scan
// Fast mailbox: 8-slot sliding window per batch, written with PLAIN stores
// (land in the producer's XCD L2; all 32 WGs of a batch-pair share that XCD
// under the %8 round-robin) and polled with sc0 loads (L1-bypass, L2-served,
// ~250 cy vs ~800+ to IF$). Slot sign flips every 8-step wrap (epoch parity)
// so stale slots can't read as ready; WG skew is <=1 step (each WG needs the
// full h(tau) before computing h(tau+1)), so an 8-deep window is safe.
// Agent/IF$ slow path kept for correctness + liveness (checked every 4th
// round) -> never depends on the blockIdx->XCD mapping (G16).
__global__ __attribute__((amdgpu_flat_work_group_size(256, 256)))
__attribute__((amdgpu_waves_per_eu(1, 1)))
void k_scan(
    const float* __restrict__ W_ih, const float* __restrict__ W_hh,
    const float* __restrict__ b_ih, const float* __restrict__ b_hh,
    float* __restrict__ Bbuf,   // slow: xproj layer1 -> h1+2 (in-place)
    float* __restrict__ Abuf,   // slow: h2+2 (O2, encoded)
    float* __restrict__ BF,     // fast: [NB][8][DD] h1 window (parity-signed)
    float* __restrict__ AF)     // fast: [NB][8][DD] h2 window
{
  const int g = blockIdx.x;
  const int bp = g & 7;            // batch-pair -> one XCD under %8 round-robin
  const int rg = g >> 3;
  const int tid = threadIdx.x;
  const int bb = tid >> 7;
  const int rl = (tid >> 3) & 15;
  const int part = tid & 7;
  const int ctid = tid & 127;
  const int row = rg * 16 + rl;
  const int bmy = bp + 8 * bb;
  const bool leader = (part == 0);

  __shared__ __align__(16) float hS1[2][2][8 * 68];
  __shared__ __align__(16) float hS2[2][2][8 * 68];
  __shared__ uint4 W2P[8 * 128];
  __shared__ uint4 W3P[8 * 128];

  float w1[64];
  {
    const volatile float* p1 = W_hh + (long)row * DD + part * 64;
    #pragma unroll
    for (int q = 0; q < 64; ++q) w1[q] = p1[q];
  }
  if (tid < 128) {
    const int brow = rg * 16 + (ctid >> 3);
    const int bpart = ctid & 7;
    const float* p2 = W_ih + (long)DD * DD + (long)brow * DD + bpart * 64;
    const float* p3 = W_hh + (long)DD * DD + (long)brow * DD + bpart * 64;
    for (int t4 = 0; t4 < 8; ++t4) {
      uint4 u2, u3;
      u2.x = pk(p2[t4*8+0], p2[t4*8+1]); u2.y = pk(p2[t4*8+2], p2[t4*8+3]);
      u2.z = pk(p2[t4*8+4], p2[t4*8+5]); u2.w = pk(p2[t4*8+6], p2[t4*8+7]);
      u3.x = pk(p3[t4*8+0], p3[t4*8+1]); u3.y = pk(p3[t4*8+2], p3[t4*8+3]);
      u3.z = pk(p3[t4*8+4], p3[t4*8+5]); u3.w = pk(p3[t4*8+6], p3[t4*8+7]);
      W2P[t4 * 128 + ctid] = u2;
      W3P[t4 * 128 + ctid] = u3;
    }
  }
  const float bias2 = b_ih[DD + row] + b_hh[DD + row];
  float xin2_d1 = 0.f;

  float* Bb = Bbuf + (long)bmy * LL * DD;
  float* Ab = Abuf + (long)bmy * LL * DD;
  float* BFb = BF + (long)bmy * 8 * DD;   // producer-side fast windows
  float* AFb = AF + (long)bmy * 8 * DD;

  // staging role: sel 0/1 -> h1 of batch bp/bp+8 ; sel 2/3 -> h2 of bp/bp+8
  const int sel = tid >> 6;
  const int tl = tid & 63;
  const int sbat = bp + (sel & 1) * 8;
  const float* sslow = ((sel < 2) ? Bbuf : Abuf) + (long)sbat * LL * DD;
  const float* sfast = ((sel < 2) ? BF : AF) + (long)sbat * 8 * DD;
  const int ldsw = (tl >> 3) * 68 + (tl & 7) * 8;

  float xpv = 0.f;
  if (leader) xpv = Bb[row];
  __syncthreads();

  for (int tau = 0; tau <= LL + 1; ++tau) {
    const int cur = tau & 1, nxt = cur ^ 1;
    const float sg1 = ((tau >> 3) & 1) ? -1.f : 1.f;          // h1 slot parity

    // ---- M1: h1(tau) = tanh(xproj + w1 . h1(tau-1)) — critical chain ----
    if (tau < LL) {
      float y = 0.f;
      if (tau >= 1) {
        const float4* hp = (const float4*)&hS1[cur][bb][part * 68];
        float y0 = 0.f, y1 = 0.f, y2 = 0.f, y3 = 0.f;
        #pragma unroll
        for (int q = 0; q < 16; ++q) {
          float4 h4 = hp[q];
          y0 += w1[4*q+0] * h4.x; y1 += w1[4*q+1] * h4.y;
          y2 += w1[4*q+2] * h4.z; y3 += w1[4*q+3] * h4.w;
        }
        y = (y0 + y1) + (y2 + y3);
      }
      y = wave_red8(y);
      if (leader) {
        float hv = fast_tanh(xpv + y);
        fast_st(BFb + (tau & 7) * DD + row, sg1 * (hv + 2.0f));  // L2 mailbox
        enc_st(Bb + (long)tau * DD + row, hv);                   // IF$ truth
      }
    }

    // ---- early agent probes on the slow path (waitcnt deferred past M3/M2) ----
    const int tstep = (sel < 2) ? tau : (tau - 2);
    const bool need = (sel < 2) ? (tau < LL) : (tau >= 2);
    const float sgp = ((tstep >> 3) & 1) ? -1.f : 1.f;
    const float* fsrc = sfast + (tstep & 7) * DD + tl * 8;
    const float* ssrc = sslow + (long)(tstep < 0 ? 0 : tstep) * DD + tl * 8;
    unsigned long long u0 = 0, u1 = 0, u2 = 0, u3 = 0;
    if (need) { u0 = ald64(ssrc); u1 = ald64(ssrc + 2); u2 = ald64(ssrc + 4); u3 = ald64(ssrc + 6); }
    if (leader && tau + 1 < LL) xpv = Bb[(long)(tau + 1) * DD + row];

    // ---- M3: h2(tau-2) = tanh(xin2(tau-2) + w3 . h2(tau-3)) ----
    if (tau >= 2) {
      float y = 0.f;
      if (tau >= 3) y = dot64_bf16(W3P, ctid, &hS2[cur][bb][part * 68]);
      y = wave_red8(y);
      if (leader) {
        float hv = fast_tanh(xin2_d1 + y);
        const int t2 = tau - 2;
        const float sg2 = ((t2 >> 3) & 1) ? -1.f : 1.f;
        fast_st(AFb + (t2 & 7) * DD + row, sg2 * (hv + 2.0f));
        enc_st(Ab + (long)t2 * DD + row, hv);
      }
    }
    // ---- M2: xin2(tau-1) = w2 . h1(tau-1) + bias2 (register chain) ----
    if (tau >= 1 && tau <= LL) {
      float y = dot64_bf16(W2P, ctid, &hS1[cur][bb][part * 68]);
      y = wave_red8(y);
      xin2_d1 = y + bias2;
    }

    // ---- check probes; spin fast/L2 mailbox with slow/IF$ liveness fallback ----
    if (need) {
      float4 Ra = make_float4(u64lo(u0), u64hi(u0), u64lo(u1), u64hi(u1));
      float4 Rb = make_float4(u64lo(u2), u64hi(u2), u64lo(u3), u64hi(u3));
      if (!rdy8(Ra, Rb)) {
        int rounds = 0;
        float4 A, Bv;
        for (;;) {
          ld2x16_sc0(fsrc, A, Bv);           // local-L2 mailbox poll (~250 cy)
          Ra = s4(A, sgp); Rb = s4(Bv, sgp);
          if (rdy8(Ra, Rb)) break;
          if ((++rounds & 3) == 0) {         // agent fallback: liveness (G16)
            unsigned long long v0 = ald64(ssrc), v1 = ald64(ssrc + 2);
            unsigned long long v2 = ald64(ssrc + 4), v3 = ald64(ssrc + 6);
            float4 Sa = make_float4(u64lo(v0), u64hi(v0), u64lo(v1), u64hi(v1));
            float4 Sb = make_float4(u64lo(v2), u64hi(v2), u64lo(v3), u64hi(v3));
            if (rdy8(Sa, Sb)) { Ra = Sa; Rb = Sb; break; }
          }
        }
      }
      float* dst = ((sel < 2) ? &hS1[nxt][sel & 1][0] : &hS2[nxt][sel & 1][0]) + ldsw;
      ((float4*)dst)[0] = make_float4(Ra.x - 2.f, Ra.y - 2.f, Ra.z - 2.f, Ra.w - 2.f);
      ((float4*)dst)[1] = make_float4(Rb.x - 2.f, Rb.y - 2.f, Rb.z - 2.f, Rb.w - 2.f);
    }
    __syncthreads();
  }
}

// ------------------------------------------- attention row @ eos + decode head
__global__ __launch_bounds__(256) void k_attn(
    const float* __restrict__ O2, const int* __restrict__ eos,
    const float* __restrict__ Wc, const float* __restrict__ bc,
    const float* __restrict__ Wd, const float* __restrict__ bd,
    float* __restrict__ out)
{
  const int b = blockIdx.x;
  const int tid = threadIdx.x;
  const int te = eos[b];
  __shared__ __align__(16) float q[DD];
  __shared__ float ps[LL];
  __shared__ float red[256];
  __shared__ __align__(16) float din[2 * DD];
  __shared__ __align__(16) float dvec[DD];
  const float* Ob = O2 + (long)b * LL * DD;
  const float4* Ob4 = (const float4*)Ob;

  float qpart = 0.f;
  for (int i = tid; i < DD; i += 256) {
    float v = Ob[(long)te * DD + i] - 2.0f;
    q[i] = v; qpart += v;
  }
  red[tid] = qpart; __syncthreads();
  for (int off = 128; off > 0; off >>= 1) {
    if (tid < off) red[tid] += red[tid + off];
    __syncthreads();
  }
  const float qsum = red[0];
  __syncthreads();
  const float4* q4 = (const float4*)q;

  for (int ss = tid; ss < LL; ss += 256) {
    float sc = -1.0e9f;
    if (ss < te) {
      float4 acc = {0.f, 0.f, 0.f, 0.f};
      for (int kq = 0; kq < 128; ++kq) {
        float4 o = Ob4[ss * 128 + kq];
        float4 qq = q4[kq];
        acc.x += o.x*qq.x; acc.y += o.y*qq.y; acc.z += o.z*qq.z; acc.w += o.w*qq.w;
      }
      sc = acc.x + acc.y + acc.z + acc.w - 2.0f * qsum;
    }
    ps[ss] = sc;
  }
  __syncthreads();
  float m = -3.0e38f;
  for (int ss = tid; ss < LL; ss += 256) m = fmaxf(m, ps[ss]);
  red[tid] = m; __syncthreads();
  for (int off = 128; off > 0; off >>= 1) {
    if (tid < off) red[tid] = fmaxf(red[tid], red[tid + off]);
    __syncthreads();
  }
  m = red[0]; __syncthreads();
  float lsum = 0.f;
  for (int ss = tid; ss < LL; ss += 256) {
    float e = expf(ps[ss] - m);
    ps[ss] = e; lsum += e;
  }
  __syncthreads();
  red[tid] = lsum; __syncthreads();
  for (int off = 128; off > 0; off >>= 1) {
    if (tid < off) red[tid] += red[tid + off];
    __syncthreads();
  }
  const float inv = 1.0f / red[0];
  __syncthreads();
  for (int ss = tid; ss < LL; ss += 256) ps[ss] *= inv;
  __syncthreads();

  if (tid < 128) {
    float4 acc = {0.f, 0.f, 0.f, 0.f};
    for (int ss = 0; ss < LL; ++ss) {
      float p = ps[ss];
      if (p != 0.0f) {
        float4 o = Ob4[ss * 128 + tid];
        acc.x += p*o.x; acc.y += p*o.y; acc.z += p*o.z; acc.w += p*o.w;
      }
    }
    acc.x -= 2.0f; acc.y -= 2.0f; acc.z -= 2.0f; acc.w -= 2.0f;
    ((float4*)din)[tid] = acc;
  } else {
    const int c = tid - 128;
    ((float4*)din)[128 + c] = q4[c];
  }
  __syncthreads();

  const float4* din4 = (const float4*)din;
  for (int jj = tid; jj < DD; jj += 256) {
    const float4* wrow = (const float4*)(Wc + (long)jj * 2 * DD);
    float4 acc = {0.f, 0.f, 0.f, 0.f};
    for (int iq = 0; iq < 256; ++iq) {
      float4 w = wrow[iq]; float4 d = din4[iq];
      acc.x += w.x*d.x; acc.y += w.y*d.y; acc.z += w.z*d.z; acc.w += w.w*d.w;
    }
    dvec[jj] = bc[jj] + acc.x + acc.y + acc.z + acc.w;
  }
  __syncthreads();

  if (tid < NCLS) {
    const float4* wrow = (const float4*)(Wd + (long)tid * DD);
    const float4* dv4 = (const float4*)dvec;
    float4 acc = {0.f, 0.f, 0.f, 0.f};
    for (int iq = 0; iq < 128; ++iq) {
      float4 w = wrow[iq]; float4 d = dv4[iq];
      acc.x += w.x*d.x; acc.y += w.y*d.y; acc.z += w.z*d.z; acc.w += w.w*d.w;
    }
    out[b * NCLS + tid] = bd[tid] + acc.x + acc.y + acc.z + acc.w;
  }
}

extern "C" void kernel_launch(void* const* d_in, const int* in_sizes, int n_in,
                              void* d_out, int out_size, void* d_ws, size_t ws_size,
                              hipStream_t stream)
{
  const int*   x    = (const int*)  d_in[0];
  const int*   eos  = (const int*)  d_in[1];
  const float* emb  = (const float*)d_in[2];
  const float* W_ih = (const float*)d_in[3];
  const float* W_hh = (const float*)d_in[4];
  const float* b_ih = (const float*)d_in[5];
  const float* b_hh = (const float*)d_in[6];
  const float* Wc   = (const float*)d_in[7];
  const float* bc   = (const float*)d_in[8];
  const float* Wd   = (const float*)d_in[9];
  const float* bd   = (const float*)d_in[10];
  float* out = (float*)d_out;

  // ws: Abuf(32M) | Bbuf(32M) | BF(256K) | AF(256K). Poison 0xAA fails both
  // readiness encodings (|v| < 1) => "not ready".
  float* Abuf = (float*)d_ws;
  float* Bbuf = Abuf + (size_t)NB * LL * DD;
  float* BF   = Bbuf + (size_t)NB * LL * DD;
  float* AF   = BF + (size_t)NB * 8 * DD;

  k_gemm_embed<<<2048, 256, 0, stream>>>(x, emb, W_ih, b_ih, b_hh, Bbuf);
  k_scan<<<256, 256, 0, stream>>>(W_ih, W_hh, b_ih, b_hh, Bbuf, Abuf, BF, AF);
  k_attn<<<NB, 256, 0, stream>>>(Abuf, eos, Wc, bc, Wd, bd, out);
}